// Round 15
// baseline (190.330 us; speedup 1.0000x reference)
//
#include <hip/hip_runtime.h>
#include <cstdint>
#include <cstddef>

typedef unsigned short u16;
typedef __bf16 bf16x8 __attribute__((ext_vector_type(8)));
typedef float  f32x4  __attribute__((ext_vector_type(4)));
typedef float  f32x16 __attribute__((ext_vector_type(16)));
typedef unsigned u32x4 __attribute__((ext_vector_type(4)));

#define DEV __device__ __forceinline__

#define B_  2
#define S_  2048
#define DM  1024
#define H_  16
#define DK  64
#define M_  (B_ * S_)   // 4096

#if __has_builtin(__builtin_amdgcn_exp2f)
#define EXP2(x) __builtin_amdgcn_exp2f(x)
#else
#define EXP2(x) exp2f(x)
#endif

// ---------------- workspace layout (bytes) ----------------
constexpr size_t OFF_QBF  = 0;                                  // Q proj out bf16 [M][DM]  (also XVBF)
constexpr size_t OFF_KBF  = OFF_QBF  + (size_t)M_ * DM * 2;     // K bf16 [B][S][DK]
constexpr size_t OFF_VBF  = OFF_KBF  + (size_t)M_ * DK * 2;     // V bf16 [B][S][DK]
constexpr size_t OFF_KF   = OFF_VBF  + (size_t)M_ * DK * 2;     // K frag-linear (rows bit2<->bit3 permuted)
constexpr size_t OFF_VF   = OFF_KF   + (size_t)M_ * DK * 2;     // V frag-linear
constexpr size_t OFF_AOBF = OFF_VF   + (size_t)M_ * DK * 2;     // attn out bf16 [M][DM]   (also XKBF)
constexpr size_t OFF_WQT  = OFF_AOBF + (size_t)M_ * DM * 2;     // Wq^T bf16 [DM][DM]
constexpr size_t OFF_WOT  = OFF_WQT  + (size_t)DM * DM * 2;     // Wo^T bf16 [DM][DM]
constexpr size_t OFF_XQBF = OFF_WOT  + (size_t)DM * DM * 2;     // inputs_q bf16 [M][DM]
constexpr size_t OFF_WKT  = OFF_XQBF + (size_t)M_ * DM * 2;     // Wk^T bf16 [DK][DM]
constexpr size_t OFF_WVT  = OFF_WKT  + (size_t)DK * DM * 2;     // Wv^T bf16 [DK][DM]

// ---------------- helpers ----------------
DEV u16 f2bf(float f) {                 // RNE f32 -> bf16
  unsigned u = __float_as_uint(f);
  u += 0x7fffu + ((u >> 16) & 1u);
  return (u16)(u >> 16);
}

DEV unsigned cvtpk(float lo, float hi) { // pack 2 f32 -> 2 bf16 (lo in low 16)
  return (unsigned)f2bf(lo) | ((unsigned)f2bf(hi) << 16);
}

DEV unsigned cvtpk_hw(float lo, float hi) { // v_cvt_pk_bf16_f32 (1 instr)
  unsigned r;
  asm("v_cvt_pk_bf16_f32 %0, %1, %2" : "=v"(r) : "v"(lo), "v"(hi));
  return r;
}

DEV void gload_lds16(const void* g, void* l) {
  __builtin_amdgcn_global_load_lds(
      (const __attribute__((address_space(1))) unsigned int*)g,
      (__attribute__((address_space(3))) unsigned int*)l, 16, 0, 0);
}

// ---------------- cast 3x f32 -> bf16, 8 elems/thread ----------------
__global__ __launch_bounds__(256) void cast3_bf16_kernel(
    const float* __restrict__ ia, const float* __restrict__ ib,
    const float* __restrict__ ic, u16* __restrict__ oa,
    u16* __restrict__ ob, u16* __restrict__ oc, int n8) {
  const int stride = gridDim.x * blockDim.x;
  for (int i = blockIdx.x * blockDim.x + threadIdx.x; i < 3 * n8; i += stride) {
    const float* in; u16* out; int k;
    if (i < n8)            { in = ia; out = oa; k = i; }
    else if (i < 2 * n8)   { in = ib; out = ob; k = i - n8; }
    else                   { in = ic; out = oc; k = i - 2 * n8; }
    float4 a = ((const float4*)in)[2 * k];
    float4 b = ((const float4*)in)[2 * k + 1];
    uint4 o;
    o.x = cvtpk(a.x, a.y);
    o.y = cvtpk(a.z, a.w);
    o.z = cvtpk(b.x, b.y);
    o.w = cvtpk(b.z, b.w);
    ((uint4*)out)[k] = o;
  }
}

// ---------------- transpose + cast W[R][C] f32 -> WT[C][R] bf16 ----------------
__global__ void transpose_cast_kernel(const float* __restrict__ W,
                                      u16* __restrict__ WT, int R, int C) {
  __shared__ u16 tile[32][33];
  const int c0 = blockIdx.x * 32, r0 = blockIdx.y * 32;
  for (int i = threadIdx.y; i < 32; i += 8)
    tile[i][threadIdx.x] = f2bf(W[(size_t)(r0 + i) * C + c0 + threadIdx.x]);
  __syncthreads();
  for (int i = threadIdx.y; i < 32; i += 8)
    WT[(size_t)(c0 + i) * R + r0 + threadIdx.x] = tile[threadIdx.x][i];
}

// ---------------- K/V projection via MFMA ----------------
__global__ __launch_bounds__(256) void kvproj_kernel(
    const u16* __restrict__ Xk, const u16* __restrict__ Xv,
    const u16* __restrict__ WkT, const u16* __restrict__ WvT,
    const float* __restrict__ bk, const float* __restrict__ bv,
    u16* __restrict__ Kout, u16* __restrict__ Vout) {
  __shared__ __align__(16) u16 At[64 * 32];
  __shared__ __align__(16) u16 Bt[64 * 32];
  const int sel = blockIdx.y;
  const u16* X  = sel ? Xv : Xk;
  const u16* WT = sel ? WvT : WkT;
  const float* bias = sel ? bv : bk;
  u16* out = sel ? Vout : Kout;

  const int tid = threadIdx.x, wave = tid >> 6, lane = tid & 63;
  const int g = lane >> 4, c = lane & 15;
  const int wm = wave >> 1, wn = wave & 1;
  const int bm = blockIdx.x;
  f32x4 acc[2][2] = {};

  const int row = tid >> 2, sd = tid & 3;
  const int kc = ((sd ^ (row & 3)) * 8);
  const u16* Asrc = X  + (size_t)(bm * 64 + row) * DM + kc;
  const u16* Bsrc = WT + (size_t)row * DM + kc;

  for (int k0 = 0; k0 < DM; k0 += 32) {
    __syncthreads();
    gload_lds16(Asrc + k0, At + wave * 512);
    gload_lds16(Bsrc + k0, Bt + wave * 512);
    asm volatile("s_waitcnt vmcnt(0)" ::: "memory");
    __syncthreads();

    bf16x8 af[2], bfr[2];
#pragma unroll
    for (int mf = 0; mf < 2; ++mf) {
      const int ra = wm * 32 + mf * 16 + c;
      af[mf] = *(const bf16x8*)(At + ra * 32 + ((g ^ (ra & 3)) * 8));
    }
#pragma unroll
    for (int nf = 0; nf < 2; ++nf) {
      const int rb = wn * 32 + nf * 16 + c;
      bfr[nf] = *(const bf16x8*)(Bt + rb * 32 + ((g ^ (rb & 3)) * 8));
    }
#pragma unroll
    for (int mf = 0; mf < 2; ++mf)
#pragma unroll
      for (int nf = 0; nf < 2; ++nf)
        acc[mf][nf] = __builtin_amdgcn_mfma_f32_16x16x32_bf16(
            af[mf], bfr[nf], acc[mf][nf], 0, 0, 0);
  }

#pragma unroll
  for (int nf = 0; nf < 2; ++nf) {
    const int col = wn * 32 + nf * 16 + c;
    const float bs = bias[col];
#pragma unroll
    for (int mf = 0; mf < 2; ++mf)
#pragma unroll
      for (int r = 0; r < 4; ++r)
        out[(size_t)(bm * 64 + wm * 32 + mf * 16 + g * 4 + r) * DK + col] =
            f2bf(acc[mf][nf][r] + bs);
  }
}

// ---------------- repack K,V -> MFMA fragment-linear KF, VF ----------------
// K fragment row c (within each 32-row sub-block) holds K row sigma(c),
// sigma = swap bits 2<->3 -> QK^T D-regs land in PV A-operand order.
__global__ __launch_bounds__(256) void repack_kv_kernel(
    const u16* __restrict__ K, const u16* __restrict__ V,
    u16* __restrict__ KF, u16* __restrict__ VF) {
  __shared__ u16 kt[64][72];
  __shared__ u16 vt[64][72];
  const int t = blockIdx.x, b = blockIdx.y;
  const int tid = threadIdx.x;
  const u16* Kp = K + ((size_t)b * S_ + t * 64) * DK;
  const u16* Vp = V + ((size_t)b * S_ + t * 64) * DK;
#pragma unroll
  for (int p = 0; p < 2; ++p) {
    const int id = tid + p * 256;          // 0..511
    const int row = id >> 3, ch = id & 7;
    *(bf16x8*)&kt[row][ch * 8] = *(const bf16x8*)(Kp + (size_t)row * DK + ch * 8);
    *(bf16x8*)&vt[row][ch * 8] = *(const bf16x8*)(Vp + (size_t)row * DK + ch * 8);
  }
  __syncthreads();
  u16* KFb = KF + (size_t)(b * 32 + t) * 4096;
  u16* VFb = VF + (size_t)(b * 32 + t) * 4096;
#pragma unroll
  for (int p = 0; p < 2; ++p) {
    const int id = tid + p * 256;          // (sub,ks,lane)
    const int sub = id >> 8, ks = (id >> 6) & 3, lane = id & 63;
    const int hi = lane >> 5, q = lane & 31;
    const int sq = (q & ~12) | ((q & 4) << 1) | ((q & 8) >> 1);  // swap bits 2,3
    *(bf16x8*)&KFb[id * 8] = *(const bf16x8*)&kt[sub * 32 + sq][ks * 16 + hi * 8];
    u16 tmp[8];
#pragma unroll
    for (int i = 0; i < 8; ++i)
      tmp[i] = vt[ks * 16 + hi * 8 + i][sub * 32 + q];
    *(bf16x8*)&VFb[id * 8] = *(const bf16x8*)tmp;
  }
}

// ---------------- 2-phase double-buffered 128x128 bf16 GEMM, BK=64 ----------------
template <int OUT_F32>
__global__ __launch_bounds__(256) void gemm_bf16_kernel(
    const u16* __restrict__ A, const u16* __restrict__ BT,
    const float* __restrict__ bias, void* __restrict__ Cout,
    int M, int N, int K, float oscale) {
  __shared__ __align__(16) u16 At[2][128 * 64];
  __shared__ __align__(16) u16 Bt[2][128 * 64];
  const int tid = threadIdx.x, wave = tid >> 6, lane = tid & 63;
  const int bm = blockIdx.x, bn = blockIdx.y;
  const int wm = wave >> 1, wn = wave & 1;
  const int g = lane >> 4, c = lane & 15;
  f32x4 acc[4][4] = {};

  int srow[4], scol[4];
#pragma unroll
  for (int i = 0; i < 4; ++i) {
    const int sid = (i * 4 + wave) * 64 + lane;
    srow[i] = sid >> 3;
    scol[i] = ((sid & 7) ^ ((sid >> 3) & 7)) * 8;
  }
  const int nt = K >> 6;

#define STAGE_G(buf, t)                                                       \
  {                                                                           \
    const int k0_ = (t) << 6;                                                 \
    _Pragma("unroll")                                                         \
    for (int i = 0; i < 4; ++i) {                                             \
      gload_lds16(A + (size_t)(bm * 128 + srow[i]) * K + k0_ + scol[i],       \
                  &At[buf][(i * 4 + wave) * 512]);                            \
      gload_lds16(BT + (size_t)(bn * 128 + srow[i]) * K + k0_ + scol[i],      \
                  &Bt[buf][(i * 4 + wave) * 512]);                            \
    }                                                                         \
  }

  STAGE_G(0, 0);
  asm volatile("s_waitcnt vmcnt(0)" ::: "memory");
  __syncthreads();

  int cur = 0;
  for (int t = 0; t < nt; ++t) {
    if (t + 1 < nt) STAGE_G(cur ^ 1, t + 1);   // issue next-tile loads FIRST
#pragma unroll
    for (int kk = 0; kk < 2; ++kk) {
      bf16x8 af[4], bfr[4];
#pragma unroll
      for (int mf = 0; mf < 4; ++mf) {
        const int row = wm * 64 + mf * 16 + c;
        af[mf] = *(const bf16x8*)(&At[cur][row * 64 + ((kk * 4 + g) ^ (row & 7)) * 8]);
      }
#pragma unroll
      for (int nf = 0; nf < 4; ++nf) {
        const int row = wn * 64 + nf * 16 + c;
        bfr[nf] = *(const bf16x8*)(&Bt[cur][row * 64 + ((kk * 4 + g) ^ (row & 7)) * 8]);
      }
#pragma unroll
      for (int mf = 0; mf < 4; ++mf)
#pragma unroll
        for (int nf = 0; nf < 4; ++nf)
          acc[mf][nf] = __builtin_amdgcn_mfma_f32_16x16x32_bf16(
              af[mf], bfr[nf], acc[mf][nf], 0, 0, 0);
    }
    asm volatile("s_waitcnt vmcnt(0)" ::: "memory");  // next tile landed
    __syncthreads();
    cur ^= 1;
  }
#undef STAGE_G

  const int colb = bn * 128 + wn * 64 + c;
  const int rowb = bm * 128 + wm * 64 + g * 4;
#pragma unroll
  for (int nf = 0; nf < 4; ++nf) {
    float bs = bias[colb + nf * 16];
#pragma unroll
    for (int mf = 0; mf < 4; ++mf) {
#pragma unroll
      for (int r = 0; r < 4; ++r) {
        size_t idx = (size_t)(rowb + mf * 16 + r) * N + colb + nf * 16;
        float v = (acc[mf][nf][r] + bs) * oscale;
        if (OUT_F32) ((float*)Cout)[idx] = v;
        else         ((u16*)Cout)[idx]   = f2bf(v);
      }
    }
  }
}

// ---------------- attn: per-tile load / per-unit compute ----------------
DEV void attn_load(const u16* kp, const u16* vp, bf16x8* kf, bf16x8* vf) {
#pragma unroll
  for (int i = 0; i < 4; ++i) {
    kf[i]     = *(const bf16x8*)(kp + i * 512);
    kf[4 + i] = *(const bf16x8*)(kp + 2048 + i * 512);
    vf[i]     = *(const bf16x8*)(vp + i * 512);
    vf[4 + i] = *(const bf16x8*)(vp + 2048 + i * 512);
  }
}

DEV void attn_comp(int t, int qrow, int hi, bool evenU, int nt,
                   const bf16x8* kf, const bf16x8* vf, const bf16x8* qf,
                   f32x16& acc0, f32x16& acc1, float& l_) {
  const int kv0 = t * 64;
  const bool diag = (t == nt - 1);
  const bool skipHi = diag && evenU;

  f32x16 sf0 = {}, sf1 = {};
  __builtin_amdgcn_s_setprio(1);
#pragma unroll
  for (int ks = 0; ks < 4; ++ks)
    sf0 = __builtin_amdgcn_mfma_f32_32x32x16_bf16(kf[ks], qf[ks], sf0, 0, 0, 0);
  if (!skipHi) {
#pragma unroll
    for (int ks = 0; ks < 4; ++ks)
      sf1 = __builtin_amdgcn_mfma_f32_32x32x16_bf16(kf[4 + ks], qf[ks], sf1, 0, 0, 0);
  }
  __builtin_amdgcn_s_setprio(0);

  if (diag) {   // causal mask; kv of reg r = 16*(r>>3) + 8*hi + (r&7)
#pragma unroll
    for (int r = 0; r < 16; ++r) {
      const int kvl = (r & 7) + 8 * hi + 16 * (r >> 3);
      if (kv0 + kvl > qrow)      sf0[r] = -1e30f;
      if (kv0 + 32 + kvl > qrow) sf1[r] = -1e30f;
    }
  }

  float rs0 = 0.f, rs1 = 0.f;
#pragma unroll
  for (int r = 0; r < 8; ++r)  { float e = EXP2(sf0[r]); sf0[r] = e; rs0 += e; }
#pragma unroll
  for (int r = 8; r < 16; ++r) { float e = EXP2(sf0[r]); sf0[r] = e; rs1 += e; }
  if (!skipHi) {
#pragma unroll
    for (int r = 0; r < 8; ++r)  { float e = EXP2(sf1[r]); sf1[r] = e; rs0 += e; }
#pragma unroll
    for (int r = 8; r < 16; ++r) { float e = EXP2(sf1[r]); sf1[r] = e; rs1 += e; }
  }
  l_ += rs0 + rs1;

  __builtin_amdgcn_s_setprio(1);
#pragma unroll
  for (int at = 0; at < 2; ++at) {
    if (at == 1 && skipHi) break;
    const f32x16& sfv = at ? sf1 : sf0;
#pragma unroll
    for (int half = 0; half < 2; ++half) {
      const int rb = half * 8;
      u32x4 pw;
      pw[0] = cvtpk_hw(sfv[rb + 0], sfv[rb + 1]);
      pw[1] = cvtpk_hw(sfv[rb + 2], sfv[rb + 3]);
      pw[2] = cvtpk_hw(sfv[rb + 4], sfv[rb + 5]);
      pw[3] = cvtpk_hw(sfv[rb + 6], sfv[rb + 7]);
      const bf16x8 pa = __builtin_bit_cast(bf16x8, pw);
      const int ksg = at * 2 + half;
      acc0 = __builtin_amdgcn_mfma_f32_32x32x16_bf16(pa, vf[ksg], acc0, 0, 0, 0);
      acc1 = __builtin_amdgcn_mfma_f32_32x32x16_bf16(pa, vf[4 + ksg], acc1, 0, 0, 0);
    }
  }
  __builtin_amdgcn_s_setprio(0);
}

// ---------------- causal MQA flash attention: split-KV, head-paired ----------------
// grid (64, 8, 2): block = (q-unit u, head pair {hp, hp+8}, b); 4 waves split
// kv tiles. Both heads share the SAME K/V fragment stream -> L2 traffic halves
// and each 16 KB fragment burst feeds 32 MFMAs. Ping-pong fragment buffers
// across tiles (R14 pattern). Combine done twice (A then B) reusing 33 KB LDS.
__global__ __launch_bounds__(256, 2) void attn_kernel(
    const u16* __restrict__ Q,   // [B*S][DM] bf16 (head h at col h*64), pre-scaled
    const u16* __restrict__ KF,  // fragment-linear K (sigma-permuted rows)
    const u16* __restrict__ VF,  // fragment-linear V
    u16* __restrict__ O) {       // [B*S][DM] bf16
  __shared__ float Ll[2][4][32];
  __shared__ float Lacc[4][32][64];   // 32 KB, reused for A then B

  const int j = blockIdx.x, hp = blockIdx.y, b = blockIdx.z;
  const int wave = threadIdx.x >> 6, lane = threadIdx.x & 63;
  const int q31 = lane & 31, hi = lane >> 5;

  const int u = (j & 1) ? (63 - (j >> 1)) : (j >> 1);
  const int qrow = u * 32 + q31;
  const int nt = (u + 2) >> 1;           // kv tiles for this q-unit
  const bool evenU = !(u & 1);

  // Q fragments for both heads (B row = q = lane&31, k = hi*8 + i)
  const u16* QpA = Q + (size_t)(b * S_ + qrow) * DM + hp * DK;
  const u16* QpB = QpA + 8 * DK;
  bf16x8 qfA[4], qfB[4];
#pragma unroll
  for (int ks = 0; ks < 4; ++ks) {
    qfA[ks] = *(const bf16x8*)(QpA + ks * 16 + hi * 8);
    qfB[ks] = *(const bf16x8*)(QpB + ks * 16 + hi * 8);
  }

  f32x16 aA0 = {}, aA1 = {}, aB0 = {}, aB1 = {};
  float lA = 0.f, lB = 0.f;

  const u16* kfb = KF + (size_t)(b * 32) * 4096 + lane * 8;
  const u16* vfb = VF + (size_t)(b * 32) * 4096 + lane * 8;

  bf16x8 kA[8], vA[8], kB[8], vB[8];
  int t = wave;
  if (t < nt)
    attn_load(kfb + (size_t)t * 4096, vfb + (size_t)t * 4096, kA, vA);
  for (; t < nt; t += 8) {
    const int t1 = t + 4;
    if (t1 < nt)
      attn_load(kfb + (size_t)t1 * 4096, vfb + (size_t)t1 * 4096, kB, vB);
    attn_comp(t, qrow, hi, evenU, nt, kA, vA, qfA, aA0, aA1, lA);
    attn_comp(t, qrow, hi, evenU, nt, kA, vA, qfB, aB0, aB1, lB);
    if (t1 < nt) {
      const int t2 = t1 + 4;
      if (t2 < nt)
        attn_load(kfb + (size_t)t2 * 4096, vfb + (size_t)t2 * 4096, kA, vA);
      attn_comp(t1, qrow, hi, evenU, nt, kB, vB, qfA, aA0, aA1, lA);
      attn_comp(t1, qrow, hi, evenU, nt, kB, vB, qfB, aB0, aB1, lB);
    }
  }

  // lane^32 combine of per-lane l partials
  lA += __shfl_xor(lA, 32);
  lB += __shfl_xor(lB, 32);
  if (hi == 0) { Ll[0][wave][q31] = lA; Ll[1][wave][q31] = lB; }

  const int row = wave * 8 + (lane >> 3);
  const int dv0 = (lane & 7) * 8;

  // ---- combine + store unit A (head hp) ----
  __syncthreads();
#pragma unroll
  for (int r = 0; r < 16; ++r) {
    const int rr = (r & 3) + 8 * (r >> 2) + 4 * hi;   // acc row (PV D layout)
    Lacc[wave][rr][q31]      = aA0[r];
    Lacc[wave][rr][32 + q31] = aA1[r];
  }
  __syncthreads();
  {
    const float Lr = Ll[0][0][row] + Ll[0][1][row] + Ll[0][2][row] + Ll[0][3][row];
    const float linv = 1.f / Lr;
    u16 ov[8];
#pragma unroll
    for (int i = 0; i < 8; ++i) {
      const float v = (Lacc[0][row][dv0 + i] + Lacc[1][row][dv0 + i] +
                       Lacc[2][row][dv0 + i] + Lacc[3][row][dv0 + i]) * linv;
      ov[i] = f2bf(v);
    }
    u16* Op = O + (size_t)(b * S_ + u * 32 + row) * DM + hp * DK + dv0;
    *(bf16x8*)Op = *(const bf16x8*)ov;
  }

  // ---- combine + store unit B (head hp+8) ----
  __syncthreads();
#pragma unroll
  for (int r = 0; r < 16; ++r) {
    const int rr = (r & 3) + 8 * (r >> 2) + 4 * hi;
    Lacc[wave][rr][q31]      = aB0[r];
    Lacc[wave][rr][32 + q31] = aB1[r];
  }
  __syncthreads();
  {
    const float Lr = Ll[1][0][row] + Ll[1][1][row] + Ll[1][2][row] + Ll[1][3][row];
    const float linv = 1.f / Lr;
    u16 ov[8];
#pragma unroll
    for (int i = 0; i < 8; ++i) {
      const float v = (Lacc[0][row][dv0 + i] + Lacc[1][row][dv0 + i] +
                       Lacc[2][row][dv0 + i] + Lacc[3][row][dv0 + i]) * linv;
      ov[i] = f2bf(v);
    }
    u16* Op = O + (size_t)(b * S_ + u * 32 + row) * DM + (hp + 8) * DK + dv0;
    *(bf16x8*)Op = *(const bf16x8*)ov;
  }
}

// ---------------- launch ----------------
extern "C" void kernel_launch(void* const* d_in, const int* in_sizes, int n_in,
                              void* d_out, int out_size, void* d_ws, size_t ws_size,
                              hipStream_t stream) {
  const float* in_q = (const float*)d_in[0];
  const float* in_k = (const float*)d_in[1];
  const float* in_v = (const float*)d_in[2];
  const float* Wq   = (const float*)d_in[3];
  const float* bq   = (const float*)d_in[4];
  const float* Wk   = (const float*)d_in[5];
  const float* bk   = (const float*)d_in[6];
  const float* Wv   = (const float*)d_in[7];
  const float* bv   = (const float*)d_in[8];
  const float* Wo   = (const float*)d_in[9];
  const float* bo   = (const float*)d_in[10];

  char* ws  = (char*)d_ws;
  u16* Qbf  = (u16*)(ws + OFF_QBF);
  u16* Kbf  = (u16*)(ws + OFF_KBF);
  u16* Vbf  = (u16*)(ws + OFF_VBF);
  u16* KFp  = (u16*)(ws + OFF_KF);
  u16* VFp  = (u16*)(ws + OFF_VF);
  u16* AObf = (u16*)(ws + OFF_AOBF);
  u16* WqT  = (u16*)(ws + OFF_WQT);
  u16* WoT  = (u16*)(ws + OFF_WOT);
  u16* Xqbf = (u16*)(ws + OFF_XQBF);
  u16* WkT  = (u16*)(ws + OFF_WKT);
  u16* WvT  = (u16*)(ws + OFF_WVT);
  u16* Xkbf = AObf;   // alias: dead before attn writes AObf
  u16* Xvbf = Qbf;    // alias: dead before Q-GEMM writes Qbf

  cast3_bf16_kernel<<<3072, 256, 0, stream>>>(in_q, in_k, in_v,
                                              Xqbf, Xkbf, Xvbf, M_ * DM / 8);

  transpose_cast_kernel<<<dim3(32, 32), dim3(32, 8), 0, stream>>>(Wq, WqT, DM, DM);
  transpose_cast_kernel<<<dim3(32, 32), dim3(32, 8), 0, stream>>>(Wo, WoT, DM, DM);
  transpose_cast_kernel<<<dim3(2, 32),  dim3(32, 8), 0, stream>>>(Wk, WkT, DM, DK);
  transpose_cast_kernel<<<dim3(2, 32),  dim3(32, 8), 0, stream>>>(Wv, WvT, DM, DK);

  kvproj_kernel<<<dim3(M_ / 64, 2), 256, 0, stream>>>(
      Xkbf, Xvbf, WkT, WvT, bk, bv, Kbf, Vbf);

  repack_kv_kernel<<<dim3(S_ / 64, B_), 256, 0, stream>>>(Kbf, Vbf, KFp, VFp);

  // Q projection, pre-scaled by 1/sqrt(dk) * log2(e) (softmax runs in exp2 domain)
  gemm_bf16_kernel<0><<<dim3(M_ / 128, DM / 128), 256, 0, stream>>>(
      Xqbf, WqT, bq, Qbf, M_, DM, DM, 0.125f * 1.44269504088896f);

  attn_kernel<<<dim3(64, 8, B_), 256, 0, stream>>>(Qbf, KFp, VFp, AObf);

  gemm_bf16_kernel<1><<<dim3(M_ / 128, DM / 128), 256, 0, stream>>>(
      AObf, WoT, bo, d_out, M_, DM, DM, 1.0f);
}

// Round 16
// 125.008 us; speedup vs baseline: 1.5225x; 1.5225x over previous
//
#include <hip/hip_runtime.h>
#include <cstdint>
#include <cstddef>

typedef unsigned short u16;
typedef __bf16 bf16x8 __attribute__((ext_vector_type(8)));
typedef float  f32x4  __attribute__((ext_vector_type(4)));
typedef float  f32x16 __attribute__((ext_vector_type(16)));
typedef unsigned u32x4 __attribute__((ext_vector_type(4)));

#define DEV __device__ __forceinline__

#define B_  2
#define S_  2048
#define DM  1024
#define H_  16
#define DK  64
#define M_  (B_ * S_)   // 4096

#if __has_builtin(__builtin_amdgcn_exp2f)
#define EXP2(x) __builtin_amdgcn_exp2f(x)
#else
#define EXP2(x) exp2f(x)
#endif

// ---------------- workspace layout (bytes) ----------------
constexpr size_t OFF_QBF  = 0;                                  // Q proj out bf16 [M][DM]  (also XVBF)
constexpr size_t OFF_KF   = OFF_QBF  + (size_t)M_ * DM * 2;     // K frag-linear (sigma rows)
constexpr size_t OFF_VF   = OFF_KF   + (size_t)M_ * DK * 2;     // V frag-linear
constexpr size_t OFF_AOBF = OFF_VF   + (size_t)M_ * DK * 2;     // attn out bf16 [M][DM]   (also XKBF)
constexpr size_t OFF_WQT  = OFF_AOBF + (size_t)M_ * DM * 2;     // Wq^T bf16 [DM][DM]
constexpr size_t OFF_WOT  = OFF_WQT  + (size_t)DM * DM * 2;     // Wo^T bf16 [DM][DM]
constexpr size_t OFF_XQBF = OFF_WOT  + (size_t)DM * DM * 2;     // inputs_q bf16 [M][DM]
constexpr size_t OFF_WKT  = OFF_XQBF + (size_t)M_ * DM * 2;     // Wk^T bf16 [DK][DM]
constexpr size_t OFF_WVT  = OFF_WKT  + (size_t)DK * DM * 2;     // Wv^T bf16 [DK][DM]

// ---------------- helpers ----------------
DEV u16 f2bf(float f) {                 // RNE f32 -> bf16
  unsigned u = __float_as_uint(f);
  u += 0x7fffu + ((u >> 16) & 1u);
  return (u16)(u >> 16);
}

DEV unsigned cvtpk(float lo, float hi) { // pack 2 f32 -> 2 bf16 (lo in low 16)
  return (unsigned)f2bf(lo) | ((unsigned)f2bf(hi) << 16);
}

DEV unsigned cvtpk_hw(float lo, float hi) { // v_cvt_pk_bf16_f32 (1 instr)
  unsigned r;
  asm("v_cvt_pk_bf16_f32 %0, %1, %2" : "=v"(r) : "v"(lo), "v"(hi));
  return r;
}

DEV void gload_lds16(const void* g, void* l) {
  __builtin_amdgcn_global_load_lds(
      (const __attribute__((address_space(1))) unsigned int*)g,
      (__attribute__((address_space(3))) unsigned int*)l, 16, 0, 0);
}

// ---------------- cast 3x f32 -> bf16, 8 elems/thread ----------------
__global__ __launch_bounds__(256) void cast3_bf16_kernel(
    const float* __restrict__ ia, const float* __restrict__ ib,
    const float* __restrict__ ic, u16* __restrict__ oa,
    u16* __restrict__ ob, u16* __restrict__ oc, int n8) {
  const int stride = gridDim.x * blockDim.x;
  for (int i = blockIdx.x * blockDim.x + threadIdx.x; i < 3 * n8; i += stride) {
    const float* in; u16* out; int k;
    if (i < n8)            { in = ia; out = oa; k = i; }
    else if (i < 2 * n8)   { in = ib; out = ob; k = i - n8; }
    else                   { in = ic; out = oc; k = i - 2 * n8; }
    float4 a = ((const float4*)in)[2 * k];
    float4 b = ((const float4*)in)[2 * k + 1];
    uint4 o;
    o.x = cvtpk(a.x, a.y);
    o.y = cvtpk(a.z, a.w);
    o.z = cvtpk(b.x, b.y);
    o.w = cvtpk(b.z, b.w);
    ((uint4*)out)[k] = o;
  }
}

// ---------------- transpose + cast W[R][C] f32 -> WT[C][R] bf16 ----------------
__global__ void transpose_cast_kernel(const float* __restrict__ W,
                                      u16* __restrict__ WT, int R, int C) {
  __shared__ u16 tile[32][33];
  const int c0 = blockIdx.x * 32, r0 = blockIdx.y * 32;
  for (int i = threadIdx.y; i < 32; i += 8)
    tile[i][threadIdx.x] = f2bf(W[(size_t)(r0 + i) * C + c0 + threadIdx.x]);
  __syncthreads();
  for (int i = threadIdx.y; i < 32; i += 8)
    WT[(size_t)(c0 + i) * R + r0 + threadIdx.x] = tile[threadIdx.x][i];
}

// ---------------- K/V projection via MFMA, fused fragment-linear emit ----------------
// grid (64, 2): x = tile index (b*32+t), y = 0:K / 1:V. Each block computes its
// 64x64 output tile and emits it DIRECTLY in fragment-linear layout (KF: sigma
// row permutation; VF: transposed), eliminating the separate repack kernel and
// the Kbf/Vbf global round-trip.
__global__ __launch_bounds__(256) void kvproj_kernel(
    const u16* __restrict__ Xk, const u16* __restrict__ Xv,
    const u16* __restrict__ WkT, const u16* __restrict__ WvT,
    const float* __restrict__ bk, const float* __restrict__ bv,
    u16* __restrict__ KF, u16* __restrict__ VF) {
  __shared__ __align__(16) u16 At[64 * 32];
  __shared__ __align__(16) u16 Bt[64 * 32];
  __shared__ u16 stage[64][72];
  const int sel = blockIdx.y;
  const u16* X  = sel ? Xv : Xk;
  const u16* WT = sel ? WvT : WkT;
  const float* bias = sel ? bv : bk;

  const int tid = threadIdx.x, wave = tid >> 6, lane = tid & 63;
  const int g = lane >> 4, c = lane & 15;
  const int wm = wave >> 1, wn = wave & 1;
  const int bm = blockIdx.x;
  f32x4 acc[2][2] = {};

  const int row = tid >> 2, sd = tid & 3;
  const int kc = ((sd ^ (row & 3)) * 8);
  const u16* Asrc = X  + (size_t)(bm * 64 + row) * DM + kc;
  const u16* Bsrc = WT + (size_t)row * DM + kc;

  for (int k0 = 0; k0 < DM; k0 += 32) {
    __syncthreads();
    gload_lds16(Asrc + k0, At + wave * 512);
    gload_lds16(Bsrc + k0, Bt + wave * 512);
    asm volatile("s_waitcnt vmcnt(0)" ::: "memory");
    __syncthreads();

    bf16x8 af[2], bfr[2];
#pragma unroll
    for (int mf = 0; mf < 2; ++mf) {
      const int ra = wm * 32 + mf * 16 + c;
      af[mf] = *(const bf16x8*)(At + ra * 32 + ((g ^ (ra & 3)) * 8));
    }
#pragma unroll
    for (int nf = 0; nf < 2; ++nf) {
      const int rb = wn * 32 + nf * 16 + c;
      bfr[nf] = *(const bf16x8*)(Bt + rb * 32 + ((g ^ (rb & 3)) * 8));
    }
#pragma unroll
    for (int mf = 0; mf < 2; ++mf)
#pragma unroll
      for (int nf = 0; nf < 2; ++nf)
        acc[mf][nf] = __builtin_amdgcn_mfma_f32_16x16x32_bf16(
            af[mf], bfr[nf], acc[mf][nf], 0, 0, 0);
  }

  // stage D-layout output (bias added) into LDS
  __syncthreads();
#pragma unroll
  for (int nf = 0; nf < 2; ++nf) {
    const int col = wn * 32 + nf * 16 + c;
    const float bs = bias[col];
#pragma unroll
    for (int mf = 0; mf < 2; ++mf)
#pragma unroll
      for (int r = 0; r < 4; ++r)
        stage[wm * 32 + mf * 16 + g * 4 + r][col] = f2bf(acc[mf][nf][r] + bs);
  }
  __syncthreads();

  // fragment-linear emit (same mapping as the proven repack kernel)
  u16* outF = (sel ? VF : KF) + (size_t)bm * 4096;
#pragma unroll
  for (int p = 0; p < 2; ++p) {
    const int id = tid + p * 256;          // (sub,ks,lane)
    const int sub = id >> 8, ks = (id >> 6) & 3, ln = id & 63;
    const int hi2 = ln >> 5, q = ln & 31;
    if (!sel) {   // K: sigma = swap bits 2<->3 of q
      const int sq = (q & ~12) | ((q & 4) << 1) | ((q & 8) >> 1);
      *(bf16x8*)&outF[id * 8] = *(const bf16x8*)&stage[sub * 32 + sq][ks * 16 + hi2 * 8];
    } else {      // V: transposed
      u16 tmp[8];
#pragma unroll
      for (int i = 0; i < 8; ++i)
        tmp[i] = stage[ks * 16 + hi2 * 8 + i][sub * 32 + q];
      *(bf16x8*)&outF[id * 8] = *(const bf16x8*)tmp;
    }
  }
}

// ---------------- 2-phase double-buffered 128x128 bf16 GEMM, BK=64 ----------------
template <int OUT_F32>
__global__ __launch_bounds__(256) void gemm_bf16_kernel(
    const u16* __restrict__ A, const u16* __restrict__ BT,
    const float* __restrict__ bias, void* __restrict__ Cout,
    int M, int N, int K, float oscale) {
  __shared__ __align__(16) u16 At[2][128 * 64];
  __shared__ __align__(16) u16 Bt[2][128 * 64];
  const int tid = threadIdx.x, wave = tid >> 6, lane = tid & 63;
  const int bm = blockIdx.x, bn = blockIdx.y;
  const int wm = wave >> 1, wn = wave & 1;
  const int g = lane >> 4, c = lane & 15;
  f32x4 acc[4][4] = {};

  int srow[4], scol[4];
#pragma unroll
  for (int i = 0; i < 4; ++i) {
    const int sid = (i * 4 + wave) * 64 + lane;
    srow[i] = sid >> 3;
    scol[i] = ((sid & 7) ^ ((sid >> 3) & 7)) * 8;
  }
  const int nt = K >> 6;

#define STAGE_G(buf, t)                                                       \
  {                                                                           \
    const int k0_ = (t) << 6;                                                 \
    _Pragma("unroll")                                                         \
    for (int i = 0; i < 4; ++i) {                                             \
      gload_lds16(A + (size_t)(bm * 128 + srow[i]) * K + k0_ + scol[i],       \
                  &At[buf][(i * 4 + wave) * 512]);                            \
      gload_lds16(BT + (size_t)(bn * 128 + srow[i]) * K + k0_ + scol[i],      \
                  &Bt[buf][(i * 4 + wave) * 512]);                            \
    }                                                                         \
  }

  STAGE_G(0, 0);
  asm volatile("s_waitcnt vmcnt(0)" ::: "memory");
  __syncthreads();

  int cur = 0;
  for (int t = 0; t < nt; ++t) {
    if (t + 1 < nt) STAGE_G(cur ^ 1, t + 1);   // issue next-tile loads FIRST
#pragma unroll
    for (int kk = 0; kk < 2; ++kk) {
      bf16x8 af[4], bfr[4];
#pragma unroll
      for (int mf = 0; mf < 4; ++mf) {
        const int row = wm * 64 + mf * 16 + c;
        af[mf] = *(const bf16x8*)(&At[cur][row * 64 + ((kk * 4 + g) ^ (row & 7)) * 8]);
      }
#pragma unroll
      for (int nf = 0; nf < 4; ++nf) {
        const int row = wn * 64 + nf * 16 + c;
        bfr[nf] = *(const bf16x8*)(&Bt[cur][row * 64 + ((kk * 4 + g) ^ (row & 7)) * 8]);
      }
#pragma unroll
      for (int mf = 0; mf < 4; ++mf)
#pragma unroll
        for (int nf = 0; nf < 4; ++nf)
          acc[mf][nf] = __builtin_amdgcn_mfma_f32_16x16x32_bf16(
              af[mf], bfr[nf], acc[mf][nf], 0, 0, 0);
    }
    asm volatile("s_waitcnt vmcnt(0)" ::: "memory");  // next tile landed
    __syncthreads();
    cur ^= 1;
  }
#undef STAGE_G

  const int colb = bn * 128 + wn * 64 + c;
  const int rowb = bm * 128 + wm * 64 + g * 4;
#pragma unroll
  for (int nf = 0; nf < 4; ++nf) {
    float bs = bias[colb + nf * 16];
#pragma unroll
    for (int mf = 0; mf < 4; ++mf) {
#pragma unroll
      for (int r = 0; r < 4; ++r) {
        size_t idx = (size_t)(rowb + mf * 16 + r) * N + colb + nf * 16;
        float v = (acc[mf][nf][r] + bs) * oscale;
        if (OUT_F32) ((float*)Cout)[idx] = v;
        else         ((u16*)Cout)[idx]   = f2bf(v);
      }
    }
  }
}

// ---------------- attn: per-tile load / compute building blocks (R14 proven) ----------------
DEV void attn_load(const u16* kp, const u16* vp, bf16x8* kf, bf16x8* vf) {
#pragma unroll
  for (int i = 0; i < 4; ++i) {
    kf[i]     = *(const bf16x8*)(kp + i * 512);
    kf[4 + i] = *(const bf16x8*)(kp + 2048 + i * 512);
    vf[i]     = *(const bf16x8*)(vp + i * 512);
    vf[4 + i] = *(const bf16x8*)(vp + 2048 + i * 512);
  }
}

DEV void attn_comp(int t, int qrow, int hi, bool evenU, int nt,
                   const bf16x8* kf, const bf16x8* vf, const bf16x8* qf,
                   f32x16& acc0, f32x16& acc1, float& l_) {
  const int kv0 = t * 64;
  const bool diag = (t == nt - 1);
  const bool skipHi = diag && evenU;

  f32x16 sf0 = {}, sf1 = {};
  __builtin_amdgcn_s_setprio(1);
#pragma unroll
  for (int ks = 0; ks < 4; ++ks)
    sf0 = __builtin_amdgcn_mfma_f32_32x32x16_bf16(kf[ks], qf[ks], sf0, 0, 0, 0);
  if (!skipHi) {
#pragma unroll
    for (int ks = 0; ks < 4; ++ks)
      sf1 = __builtin_amdgcn_mfma_f32_32x32x16_bf16(kf[4 + ks], qf[ks], sf1, 0, 0, 0);
  }
  __builtin_amdgcn_s_setprio(0);

  if (diag) {   // causal mask; kv of reg r = 16*(r>>3) + 8*hi + (r&7)
#pragma unroll
    for (int r = 0; r < 16; ++r) {
      const int kvl = (r & 7) + 8 * hi + 16 * (r >> 3);
      if (kv0 + kvl > qrow)      sf0[r] = -1e30f;
      if (kv0 + 32 + kvl > qrow) sf1[r] = -1e30f;
    }
  }

  float rs0 = 0.f, rs1 = 0.f;
#pragma unroll
  for (int r = 0; r < 8; ++r)  { float e = EXP2(sf0[r]); sf0[r] = e; rs0 += e; }
#pragma unroll
  for (int r = 8; r < 16; ++r) { float e = EXP2(sf0[r]); sf0[r] = e; rs1 += e; }
  if (!skipHi) {
#pragma unroll
    for (int r = 0; r < 8; ++r)  { float e = EXP2(sf1[r]); sf1[r] = e; rs0 += e; }
#pragma unroll
    for (int r = 8; r < 16; ++r) { float e = EXP2(sf1[r]); sf1[r] = e; rs1 += e; }
  }
  l_ += rs0 + rs1;

  __builtin_amdgcn_s_setprio(1);
#pragma unroll
  for (int at = 0; at < 2; ++at) {
    if (at == 1 && skipHi) break;
    const f32x16& sfv = at ? sf1 : sf0;
#pragma unroll
    for (int half = 0; half < 2; ++half) {
      const int rb = half * 8;
      u32x4 pw;
      pw[0] = cvtpk_hw(sfv[rb + 0], sfv[rb + 1]);
      pw[1] = cvtpk_hw(sfv[rb + 2], sfv[rb + 3]);
      pw[2] = cvtpk_hw(sfv[rb + 4], sfv[rb + 5]);
      pw[3] = cvtpk_hw(sfv[rb + 6], sfv[rb + 7]);
      const bf16x8 pa = __builtin_bit_cast(bf16x8, pw);
      const int ksg = at * 2 + half;
      acc0 = __builtin_amdgcn_mfma_f32_32x32x16_bf16(pa, vf[ksg], acc0, 0, 0, 0);
      acc1 = __builtin_amdgcn_mfma_f32_32x32x16_bf16(pa, vf[4 + ksg], acc1, 0, 0, 0);
    }
  }
  __builtin_amdgcn_s_setprio(0);
}

// ---------------- causal MQA flash attention: split-KV, 2-stage pipeline (R14) ----------------
__global__ __launch_bounds__(256, 2) void attn_kernel(
    const u16* __restrict__ Q,   // [B*S][DM] bf16 (head h at col h*64), pre-scaled
    const u16* __restrict__ KF,  // fragment-linear K (sigma-permuted rows)
    const u16* __restrict__ VF,  // fragment-linear V
    u16* __restrict__ O) {       // [B*S][DM] bf16
  __shared__ float Ll[4][32];
  __shared__ float Lacc[4][32][64];   // 32 KB

  const int j = blockIdx.x, h = blockIdx.y, b = blockIdx.z;
  const int wave = threadIdx.x >> 6, lane = threadIdx.x & 63;
  const int q31 = lane & 31, hi = lane >> 5;

  const int u = (j & 1) ? (63 - (j >> 1)) : (j >> 1);
  const int qrow = u * 32 + q31;
  const int nt = (u + 2) >> 1;           // kv tiles for this q-unit
  const bool evenU = !(u & 1);

  const u16* Qp = Q + (size_t)(b * S_ + qrow) * DM + h * DK;
  bf16x8 qf[4];
#pragma unroll
  for (int ks = 0; ks < 4; ++ks)
    qf[ks] = *(const bf16x8*)(Qp + ks * 16 + hi * 8);

  f32x16 acc0 = {}, acc1 = {};
  float l_ = 0.f;

  const u16* kfb = KF + (size_t)(b * 32) * 4096 + lane * 8;
  const u16* vfb = VF + (size_t)(b * 32) * 4096 + lane * 8;

  bf16x8 kA[8], vA[8], kB[8], vB[8];
  int t = wave;
  if (t < nt)
    attn_load(kfb + (size_t)t * 4096, vfb + (size_t)t * 4096, kA, vA);
  for (; t < nt; t += 8) {
    const int t1 = t + 4;
    if (t1 < nt)
      attn_load(kfb + (size_t)t1 * 4096, vfb + (size_t)t1 * 4096, kB, vB);
    attn_comp(t, qrow, hi, evenU, nt, kA, vA, qf, acc0, acc1, l_);
    if (t1 < nt) {
      const int t2 = t1 + 4;
      if (t2 < nt)
        attn_load(kfb + (size_t)t2 * 4096, vfb + (size_t)t2 * 4096, kA, vA);
      attn_comp(t1, qrow, hi, evenU, nt, kB, vB, qf, acc0, acc1, l_);
    }
  }

  // one lane^32 combine of the per-lane l partials
  l_ += __shfl_xor(l_, 32);

  // ---- block-level combine of the 4 partials (plain sums) ----
  if (hi == 0) Ll[wave][q31] = l_;
  __syncthreads();

#pragma unroll
  for (int r = 0; r < 16; ++r) {
    const int rr = (r & 3) + 8 * (r >> 2) + 4 * hi;   // acc row (PV D layout)
    Lacc[wave][rr][q31]      = acc0[r];
    Lacc[wave][rr][32 + q31] = acc1[r];
  }
  __syncthreads();

  const int row = wave * 8 + (lane >> 3);
  const int dv0 = (lane & 7) * 8;
  const float Lr = Ll[0][row] + Ll[1][row] + Ll[2][row] + Ll[3][row];
  const float linv = 1.f / Lr;
  u16 ov[8];
#pragma unroll
  for (int i = 0; i < 8; ++i) {
    const float v = (Lacc[0][row][dv0 + i] + Lacc[1][row][dv0 + i] +
                     Lacc[2][row][dv0 + i] + Lacc[3][row][dv0 + i]) * linv;
    ov[i] = f2bf(v);
  }
  u16* Op = O + (size_t)(b * S_ + u * 32 + row) * DM + h * DK + dv0;
  *(bf16x8*)Op = *(const bf16x8*)ov;
}

// ---------------- launch ----------------
extern "C" void kernel_launch(void* const* d_in, const int* in_sizes, int n_in,
                              void* d_out, int out_size, void* d_ws, size_t ws_size,
                              hipStream_t stream) {
  const float* in_q = (const float*)d_in[0];
  const float* in_k = (const float*)d_in[1];
  const float* in_v = (const float*)d_in[2];
  const float* Wq   = (const float*)d_in[3];
  const float* bq   = (const float*)d_in[4];
  const float* Wk   = (const float*)d_in[5];
  const float* bk   = (const float*)d_in[6];
  const float* Wv   = (const float*)d_in[7];
  const float* bv   = (const float*)d_in[8];
  const float* Wo   = (const float*)d_in[9];
  const float* bo   = (const float*)d_in[10];

  char* ws  = (char*)d_ws;
  u16* Qbf  = (u16*)(ws + OFF_QBF);
  u16* KFp  = (u16*)(ws + OFF_KF);
  u16* VFp  = (u16*)(ws + OFF_VF);
  u16* AObf = (u16*)(ws + OFF_AOBF);
  u16* WqT  = (u16*)(ws + OFF_WQT);
  u16* WoT  = (u16*)(ws + OFF_WOT);
  u16* Xqbf = (u16*)(ws + OFF_XQBF);
  u16* WkT  = (u16*)(ws + OFF_WKT);
  u16* WvT  = (u16*)(ws + OFF_WVT);
  u16* Xkbf = AObf;   // alias: dead before attn writes AObf
  u16* Xvbf = Qbf;    // alias: dead before Q-GEMM writes Qbf

  cast3_bf16_kernel<<<3072, 256, 0, stream>>>(in_q, in_k, in_v,
                                              Xqbf, Xkbf, Xvbf, M_ * DM / 8);

  transpose_cast_kernel<<<dim3(32, 32), dim3(32, 8), 0, stream>>>(Wq, WqT, DM, DM);
  transpose_cast_kernel<<<dim3(32, 32), dim3(32, 8), 0, stream>>>(Wo, WoT, DM, DM);
  transpose_cast_kernel<<<dim3(2, 32),  dim3(32, 8), 0, stream>>>(Wk, WkT, DM, DK);
  transpose_cast_kernel<<<dim3(2, 32),  dim3(32, 8), 0, stream>>>(Wv, WvT, DM, DK);

  // K/V projection with fused fragment-linear emit (no separate repack)
  kvproj_kernel<<<dim3(M_ / 64, 2), 256, 0, stream>>>(
      Xkbf, Xvbf, WkT, WvT, bk, bv, KFp, VFp);

  // Q projection, pre-scaled by 1/sqrt(dk) * log2(e) (softmax runs in exp2 domain)
  gemm_bf16_kernel<0><<<dim3(M_ / 128, DM / 128), 256, 0, stream>>>(
      Xqbf, WqT, bq, Qbf, M_, DM, DM, 0.125f * 1.44269504088896f);

  attn_kernel<<<dim3(64, H_, B_), 256, 0, stream>>>(Qbf, KFp, VFp, AObf);

  gemm_bf16_kernel<1><<<dim3(M_ / 128, DM / 128), 256, 0, stream>>>(
      AObf, WoT, bo, d_out, M_, DM, DM, 1.0f);
}

// Round 17
// 118.457 us; speedup vs baseline: 1.6067x; 1.0553x over previous
//
#include <hip/hip_runtime.h>
#include <cstdint>
#include <cstddef>

typedef unsigned short u16;
typedef __bf16 bf16x8 __attribute__((ext_vector_type(8)));
typedef float  f32x4  __attribute__((ext_vector_type(4)));
typedef float  f32x16 __attribute__((ext_vector_type(16)));
typedef unsigned u32x4 __attribute__((ext_vector_type(4)));

#define DEV __device__ __forceinline__

#define B_  2
#define S_  2048
#define DM  1024
#define H_  16
#define DK  64
#define M_  (B_ * S_)   // 4096

#if __has_builtin(__builtin_amdgcn_exp2f)
#define EXP2(x) __builtin_amdgcn_exp2f(x)
#else
#define EXP2(x) exp2f(x)
#endif

// ---------------- workspace layout (bytes) ----------------
constexpr size_t OFF_QBF  = 0;                                  // Q proj out bf16 [M][DM]  (also XVBF)
constexpr size_t OFF_KF   = OFF_QBF  + (size_t)M_ * DM * 2;     // K frag-linear (sigma rows)
constexpr size_t OFF_VF   = OFF_KF   + (size_t)M_ * DK * 2;     // V frag-linear
constexpr size_t OFF_AOBF = OFF_VF   + (size_t)M_ * DK * 2;     // attn out bf16 [M][DM]   (also XKBF)
constexpr size_t OFF_WQT  = OFF_AOBF + (size_t)M_ * DM * 2;     // Wq^T bf16 [DM][DM]
constexpr size_t OFF_WOT  = OFF_WQT  + (size_t)DM * DM * 2;     // Wo^T bf16 [DM][DM]
constexpr size_t OFF_XQBF = OFF_WOT  + (size_t)DM * DM * 2;     // inputs_q bf16 [M][DM]
constexpr size_t OFF_WKT  = OFF_XQBF + (size_t)M_ * DM * 2;     // Wk^T bf16 [DK][DM]
constexpr size_t OFF_WVT  = OFF_WKT  + (size_t)DK * DM * 2;     // Wv^T bf16 [DK][DM]

// ---------------- helpers ----------------
DEV u16 f2bf(float f) {                 // RNE f32 -> bf16
  unsigned u = __float_as_uint(f);
  u += 0x7fffu + ((u >> 16) & 1u);
  return (u16)(u >> 16);
}

DEV unsigned cvtpk(float lo, float hi) { // pack 2 f32 -> 2 bf16 (lo in low 16)
  return (unsigned)f2bf(lo) | ((unsigned)f2bf(hi) << 16);
}

DEV unsigned cvtpk_hw(float lo, float hi) { // v_cvt_pk_bf16_f32 (1 instr)
  unsigned r;
  asm("v_cvt_pk_bf16_f32 %0, %1, %2" : "=v"(r) : "v"(lo), "v"(hi));
  return r;
}

DEV void gload_lds16(const void* g, void* l) {
  __builtin_amdgcn_global_load_lds(
      (const __attribute__((address_space(1))) unsigned int*)g,
      (__attribute__((address_space(3))) unsigned int*)l, 16, 0, 0);
}

// ---------------- cast 3x f32 -> bf16, 8 elems/thread ----------------
__global__ __launch_bounds__(256) void cast3_bf16_kernel(
    const float* __restrict__ ia, const float* __restrict__ ib,
    const float* __restrict__ ic, u16* __restrict__ oa,
    u16* __restrict__ ob, u16* __restrict__ oc, int n8) {
  const int stride = gridDim.x * blockDim.x;
  for (int i = blockIdx.x * blockDim.x + threadIdx.x; i < 3 * n8; i += stride) {
    const float* in; u16* out; int k;
    if (i < n8)            { in = ia; out = oa; k = i; }
    else if (i < 2 * n8)   { in = ib; out = ob; k = i - n8; }
    else                   { in = ic; out = oc; k = i - 2 * n8; }
    float4 a = ((const float4*)in)[2 * k];
    float4 b = ((const float4*)in)[2 * k + 1];
    uint4 o;
    o.x = cvtpk(a.x, a.y);
    o.y = cvtpk(a.z, a.w);
    o.z = cvtpk(b.x, b.y);
    o.w = cvtpk(b.z, b.w);
    ((uint4*)out)[k] = o;
  }
}

// ---------------- transpose + cast W[R][C] f32 -> WT[C][R] bf16 ----------------
__global__ void transpose_cast_kernel(const float* __restrict__ W,
                                      u16* __restrict__ WT, int R, int C) {
  __shared__ u16 tile[32][33];
  const int c0 = blockIdx.x * 32, r0 = blockIdx.y * 32;
  for (int i = threadIdx.y; i < 32; i += 8)
    tile[i][threadIdx.x] = f2bf(W[(size_t)(r0 + i) * C + c0 + threadIdx.x]);
  __syncthreads();
  for (int i = threadIdx.y; i < 32; i += 8)
    WT[(size_t)(c0 + i) * R + r0 + threadIdx.x] = tile[threadIdx.x][i];
}

// ---------------- K/V projection via MFMA, fused fragment-linear emit ----------------
__global__ __launch_bounds__(256) void kvproj_kernel(
    const u16* __restrict__ Xk, const u16* __restrict__ Xv,
    const u16* __restrict__ WkT, const u16* __restrict__ WvT,
    const float* __restrict__ bk, const float* __restrict__ bv,
    u16* __restrict__ KF, u16* __restrict__ VF) {
  __shared__ __align__(16) u16 At[64 * 32];
  __shared__ __align__(16) u16 Bt[64 * 32];
  __shared__ u16 stage[64][72];
  const int sel = blockIdx.y;
  const u16* X  = sel ? Xv : Xk;
  const u16* WT = sel ? WvT : WkT;
  const float* bias = sel ? bv : bk;

  const int tid = threadIdx.x, wave = tid >> 6, lane = tid & 63;
  const int g = lane >> 4, c = lane & 15;
  const int wm = wave >> 1, wn = wave & 1;
  const int bm = blockIdx.x;
  f32x4 acc[2][2] = {};

  const int row = tid >> 2, sd = tid & 3;
  const int kc = ((sd ^ (row & 3)) * 8);
  const u16* Asrc = X  + (size_t)(bm * 64 + row) * DM + kc;
  const u16* Bsrc = WT + (size_t)row * DM + kc;

  for (int k0 = 0; k0 < DM; k0 += 32) {
    __syncthreads();
    gload_lds16(Asrc + k0, At + wave * 512);
    gload_lds16(Bsrc + k0, Bt + wave * 512);
    asm volatile("s_waitcnt vmcnt(0)" ::: "memory");
    __syncthreads();

    bf16x8 af[2], bfr[2];
#pragma unroll
    for (int mf = 0; mf < 2; ++mf) {
      const int ra = wm * 32 + mf * 16 + c;
      af[mf] = *(const bf16x8*)(At + ra * 32 + ((g ^ (ra & 3)) * 8));
    }
#pragma unroll
    for (int nf = 0; nf < 2; ++nf) {
      const int rb = wn * 32 + nf * 16 + c;
      bfr[nf] = *(const bf16x8*)(Bt + rb * 32 + ((g ^ (rb & 3)) * 8));
    }
#pragma unroll
    for (int mf = 0; mf < 2; ++mf)
#pragma unroll
      for (int nf = 0; nf < 2; ++nf)
        acc[mf][nf] = __builtin_amdgcn_mfma_f32_16x16x32_bf16(
            af[mf], bfr[nf], acc[mf][nf], 0, 0, 0);
  }

  // stage D-layout output (bias added) into LDS
  __syncthreads();
#pragma unroll
  for (int nf = 0; nf < 2; ++nf) {
    const int col = wn * 32 + nf * 16 + c;
    const float bs = bias[col];
#pragma unroll
    for (int mf = 0; mf < 2; ++mf)
#pragma unroll
      for (int r = 0; r < 4; ++r)
        stage[wm * 32 + mf * 16 + g * 4 + r][col] = f2bf(acc[mf][nf][r] + bs);
  }
  __syncthreads();

  // fragment-linear emit (same mapping as the proven repack kernel)
  u16* outF = (sel ? VF : KF) + (size_t)bm * 4096;
#pragma unroll
  for (int p = 0; p < 2; ++p) {
    const int id = tid + p * 256;          // (sub,ks,lane)
    const int sub = id >> 8, ks = (id >> 6) & 3, ln = id & 63;
    const int hi2 = ln >> 5, q = ln & 31;
    if (!sel) {   // K: sigma = swap bits 2<->3 of q
      const int sq = (q & ~12) | ((q & 4) << 1) | ((q & 8) >> 1);
      *(bf16x8*)&outF[id * 8] = *(const bf16x8*)&stage[sub * 32 + sq][ks * 16 + hi2 * 8];
    } else {      // V: transposed
      u16 tmp[8];
#pragma unroll
      for (int i = 0; i < 8; ++i)
        tmp[i] = stage[ks * 16 + hi2 * 8 + i][sub * 32 + q];
      *(bf16x8*)&outF[id * 8] = *(const bf16x8*)tmp;
    }
  }
}

// ---------------- 2-phase double-buffered 128x64 bf16 GEMM, BK=64 ----------------
// grid (M/128, N/64) = 512 blocks -> 2 blocks/CU co-resident (48 KB LDS),
// so barrier drains overlap across blocks (m97-style implicit pipelining).
template <int OUT_F32>
__global__ __launch_bounds__(256) void gemm_bf16_kernel(
    const u16* __restrict__ A, const u16* __restrict__ BT,
    const float* __restrict__ bias, void* __restrict__ Cout,
    int M, int N, int K, float oscale) {
  __shared__ __align__(16) u16 At[2][128 * 64];   // 16 KB / buf
  __shared__ __align__(16) u16 Bt[2][64 * 64];    //  8 KB / buf
  const int tid = threadIdx.x, wave = tid >> 6, lane = tid & 63;
  const int bm = blockIdx.x, bn = blockIdx.y;
  const int wm = wave >> 1, wn = wave & 1;
  const int g = lane >> 4, c = lane & 15;
  f32x4 acc[4][2] = {};

  // staging maps (16B slots, source col pre-swizzled; linear LDS dest)
  int arow[4], acol[4], brow[2], bcol[2];
#pragma unroll
  for (int i = 0; i < 4; ++i) {
    const int sid = (i * 4 + wave) * 64 + lane;   // 0..1023
    arow[i] = sid >> 3;
    acol[i] = ((sid & 7) ^ ((sid >> 3) & 7)) * 8;
  }
#pragma unroll
  for (int i = 0; i < 2; ++i) {
    const int sid = (i * 4 + wave) * 64 + lane;   // 0..511
    brow[i] = sid >> 3;
    bcol[i] = ((sid & 7) ^ ((sid >> 3) & 7)) * 8;
  }
  const int nt = K >> 6;

#define STAGE_G(buf, t)                                                       \
  {                                                                           \
    const int k0_ = (t) << 6;                                                 \
    _Pragma("unroll")                                                         \
    for (int i = 0; i < 4; ++i)                                               \
      gload_lds16(A + (size_t)(bm * 128 + arow[i]) * K + k0_ + acol[i],       \
                  &At[buf][(i * 4 + wave) * 512]);                            \
    _Pragma("unroll")                                                         \
    for (int i = 0; i < 2; ++i)                                               \
      gload_lds16(BT + (size_t)(bn * 64 + brow[i]) * K + k0_ + bcol[i],       \
                  &Bt[buf][(i * 4 + wave) * 512]);                            \
  }

  STAGE_G(0, 0);
  asm volatile("s_waitcnt vmcnt(0)" ::: "memory");
  __syncthreads();

  int cur = 0;
  for (int t = 0; t < nt; ++t) {
    if (t + 1 < nt) STAGE_G(cur ^ 1, t + 1);   // issue next-tile loads FIRST
#pragma unroll
    for (int kk = 0; kk < 2; ++kk) {
      bf16x8 af[4], bfr[2];
#pragma unroll
      for (int mf = 0; mf < 4; ++mf) {
        const int row = wm * 64 + mf * 16 + c;
        af[mf] = *(const bf16x8*)(&At[cur][row * 64 + ((kk * 4 + g) ^ (row & 7)) * 8]);
      }
#pragma unroll
      for (int nf = 0; nf < 2; ++nf) {
        const int row = wn * 32 + nf * 16 + c;
        bfr[nf] = *(const bf16x8*)(&Bt[cur][row * 64 + ((kk * 4 + g) ^ (row & 7)) * 8]);
      }
#pragma unroll
      for (int mf = 0; mf < 4; ++mf)
#pragma unroll
        for (int nf = 0; nf < 2; ++nf)
          acc[mf][nf] = __builtin_amdgcn_mfma_f32_16x16x32_bf16(
              af[mf], bfr[nf], acc[mf][nf], 0, 0, 0);
    }
    asm volatile("s_waitcnt vmcnt(0)" ::: "memory");  // next tile landed
    __syncthreads();
    cur ^= 1;
  }
#undef STAGE_G

  const int colb = bn * 64 + wn * 32 + c;
  const int rowb = bm * 128 + wm * 64 + g * 4;
#pragma unroll
  for (int nf = 0; nf < 2; ++nf) {
    float bs = bias[colb + nf * 16];
#pragma unroll
    for (int mf = 0; mf < 4; ++mf) {
#pragma unroll
      for (int r = 0; r < 4; ++r) {
        size_t idx = (size_t)(rowb + mf * 16 + r) * N + colb + nf * 16;
        float v = (acc[mf][nf][r] + bs) * oscale;
        if (OUT_F32) ((float*)Cout)[idx] = v;
        else         ((u16*)Cout)[idx]   = f2bf(v);
      }
    }
  }
}

// ---------------- attn: per-tile load / compute building blocks (R14 proven) ----------------
DEV void attn_load(const u16* kp, const u16* vp, bf16x8* kf, bf16x8* vf) {
#pragma unroll
  for (int i = 0; i < 4; ++i) {
    kf[i]     = *(const bf16x8*)(kp + i * 512);
    kf[4 + i] = *(const bf16x8*)(kp + 2048 + i * 512);
    vf[i]     = *(const bf16x8*)(vp + i * 512);
    vf[4 + i] = *(const bf16x8*)(vp + 2048 + i * 512);
  }
}

DEV void attn_comp(int t, int qrow, int hi, bool evenU, int nt,
                   const bf16x8* kf, const bf16x8* vf, const bf16x8* qf,
                   f32x16& acc0, f32x16& acc1, float& l_) {
  const int kv0 = t * 64;
  const bool diag = (t == nt - 1);
  const bool skipHi = diag && evenU;

  f32x16 sf0 = {}, sf1 = {};
  __builtin_amdgcn_s_setprio(1);
#pragma unroll
  for (int ks = 0; ks < 4; ++ks)
    sf0 = __builtin_amdgcn_mfma_f32_32x32x16_bf16(kf[ks], qf[ks], sf0, 0, 0, 0);
  if (!skipHi) {
#pragma unroll
    for (int ks = 0; ks < 4; ++ks)
      sf1 = __builtin_amdgcn_mfma_f32_32x32x16_bf16(kf[4 + ks], qf[ks], sf1, 0, 0, 0);
  }
  __builtin_amdgcn_s_setprio(0);

  if (diag) {   // causal mask; kv of reg r = 16*(r>>3) + 8*hi + (r&7)
#pragma unroll
    for (int r = 0; r < 16; ++r) {
      const int kvl = (r & 7) + 8 * hi + 16 * (r >> 3);
      if (kv0 + kvl > qrow)      sf0[r] = -1e30f;
      if (kv0 + 32 + kvl > qrow) sf1[r] = -1e30f;
    }
  }

  float rs0 = 0.f, rs1 = 0.f;
#pragma unroll
  for (int r = 0; r < 8; ++r)  { float e = EXP2(sf0[r]); sf0[r] = e; rs0 += e; }
#pragma unroll
  for (int r = 8; r < 16; ++r) { float e = EXP2(sf0[r]); sf0[r] = e; rs1 += e; }
  if (!skipHi) {
#pragma unroll
    for (int r = 0; r < 8; ++r)  { float e = EXP2(sf1[r]); sf1[r] = e; rs0 += e; }
#pragma unroll
    for (int r = 8; r < 16; ++r) { float e = EXP2(sf1[r]); sf1[r] = e; rs1 += e; }
  }
  l_ += rs0 + rs1;

  __builtin_amdgcn_s_setprio(1);
#pragma unroll
  for (int at = 0; at < 2; ++at) {
    if (at == 1 && skipHi) break;
    const f32x16& sfv = at ? sf1 : sf0;
#pragma unroll
    for (int half = 0; half < 2; ++half) {
      const int rb = half * 8;
      u32x4 pw;
      pw[0] = cvtpk_hw(sfv[rb + 0], sfv[rb + 1]);
      pw[1] = cvtpk_hw(sfv[rb + 2], sfv[rb + 3]);
      pw[2] = cvtpk_hw(sfv[rb + 4], sfv[rb + 5]);
      pw[3] = cvtpk_hw(sfv[rb + 6], sfv[rb + 7]);
      const bf16x8 pa = __builtin_bit_cast(bf16x8, pw);
      const int ksg = at * 2 + half;
      acc0 = __builtin_amdgcn_mfma_f32_32x32x16_bf16(pa, vf[ksg], acc0, 0, 0, 0);
      acc1 = __builtin_amdgcn_mfma_f32_32x32x16_bf16(pa, vf[4 + ksg], acc1, 0, 0, 0);
    }
  }
  __builtin_amdgcn_s_setprio(0);
}

// ---------------- causal MQA flash attention: split-KV, 2-stage pipeline (R14) ----------------
__global__ __launch_bounds__(256, 2) void attn_kernel(
    const u16* __restrict__ Q,   // [B*S][DM] bf16 (head h at col h*64), pre-scaled
    const u16* __restrict__ KF,  // fragment-linear K (sigma-permuted rows)
    const u16* __restrict__ VF,  // fragment-linear V
    u16* __restrict__ O) {       // [B*S][DM] bf16
  __shared__ float Ll[4][32];
  __shared__ float Lacc[4][32][64];   // 32 KB

  const int j = blockIdx.x, h = blockIdx.y, b = blockIdx.z;
  const int wave = threadIdx.x >> 6, lane = threadIdx.x & 63;
  const int q31 = lane & 31, hi = lane >> 5;

  const int u = (j & 1) ? (63 - (j >> 1)) : (j >> 1);
  const int qrow = u * 32 + q31;
  const int nt = (u + 2) >> 1;           // kv tiles for this q-unit
  const bool evenU = !(u & 1);

  const u16* Qp = Q + (size_t)(b * S_ + qrow) * DM + h * DK;
  bf16x8 qf[4];
#pragma unroll
  for (int ks = 0; ks < 4; ++ks)
    qf[ks] = *(const bf16x8*)(Qp + ks * 16 + hi * 8);

  f32x16 acc0 = {}, acc1 = {};
  float l_ = 0.f;

  const u16* kfb = KF + (size_t)(b * 32) * 4096 + lane * 8;
  const u16* vfb = VF + (size_t)(b * 32) * 4096 + lane * 8;

  bf16x8 kA[8], vA[8], kB[8], vB[8];
  int t = wave;
  if (t < nt)
    attn_load(kfb + (size_t)t * 4096, vfb + (size_t)t * 4096, kA, vA);
  for (; t < nt; t += 8) {
    const int t1 = t + 4;
    if (t1 < nt)
      attn_load(kfb + (size_t)t1 * 4096, vfb + (size_t)t1 * 4096, kB, vB);
    attn_comp(t, qrow, hi, evenU, nt, kA, vA, qf, acc0, acc1, l_);
    if (t1 < nt) {
      const int t2 = t1 + 4;
      if (t2 < nt)
        attn_load(kfb + (size_t)t2 * 4096, vfb + (size_t)t2 * 4096, kA, vA);
      attn_comp(t1, qrow, hi, evenU, nt, kB, vB, qf, acc0, acc1, l_);
    }
  }

  // one lane^32 combine of the per-lane l partials
  l_ += __shfl_xor(l_, 32);

  // ---- block-level combine of the 4 partials (plain sums) ----
  if (hi == 0) Ll[wave][q31] = l_;
  __syncthreads();

#pragma unroll
  for (int r = 0; r < 16; ++r) {
    const int rr = (r & 3) + 8 * (r >> 2) + 4 * hi;   // acc row (PV D layout)
    Lacc[wave][rr][q31]      = acc0[r];
    Lacc[wave][rr][32 + q31] = acc1[r];
  }
  __syncthreads();

  const int row = wave * 8 + (lane >> 3);
  const int dv0 = (lane & 7) * 8;
  const float Lr = Ll[0][row] + Ll[1][row] + Ll[2][row] + Ll[3][row];
  const float linv = 1.f / Lr;
  u16 ov[8];
#pragma unroll
  for (int i = 0; i < 8; ++i) {
    const float v = (Lacc[0][row][dv0 + i] + Lacc[1][row][dv0 + i] +
                     Lacc[2][row][dv0 + i] + Lacc[3][row][dv0 + i]) * linv;
    ov[i] = f2bf(v);
  }
  u16* Op = O + (size_t)(b * S_ + u * 32 + row) * DM + h * DK + dv0;
  *(bf16x8*)Op = *(const bf16x8*)ov;
}

// ---------------- launch ----------------
extern "C" void kernel_launch(void* const* d_in, const int* in_sizes, int n_in,
                              void* d_out, int out_size, void* d_ws, size_t ws_size,
                              hipStream_t stream) {
  const float* in_q = (const float*)d_in[0];
  const float* in_k = (const float*)d_in[1];
  const float* in_v = (const float*)d_in[2];
  const float* Wq   = (const float*)d_in[3];
  const float* bq   = (const float*)d_in[4];
  const float* Wk   = (const float*)d_in[5];
  const float* bk   = (const float*)d_in[6];
  const float* Wv   = (const float*)d_in[7];
  const float* bv   = (const float*)d_in[8];
  const float* Wo   = (const float*)d_in[9];
  const float* bo   = (const float*)d_in[10];

  char* ws  = (char*)d_ws;
  u16* Qbf  = (u16*)(ws + OFF_QBF);
  u16* KFp  = (u16*)(ws + OFF_KF);
  u16* VFp  = (u16*)(ws + OFF_VF);
  u16* AObf = (u16*)(ws + OFF_AOBF);
  u16* WqT  = (u16*)(ws + OFF_WQT);
  u16* WoT  = (u16*)(ws + OFF_WOT);
  u16* Xqbf = (u16*)(ws + OFF_XQBF);
  u16* WkT  = (u16*)(ws + OFF_WKT);
  u16* WvT  = (u16*)(ws + OFF_WVT);
  u16* Xkbf = AObf;   // alias: dead before attn writes AObf
  u16* Xvbf = Qbf;    // alias: dead before Q-GEMM writes Qbf

  cast3_bf16_kernel<<<3072, 256, 0, stream>>>(in_q, in_k, in_v,
                                              Xqbf, Xkbf, Xvbf, M_ * DM / 8);

  transpose_cast_kernel<<<dim3(32, 32), dim3(32, 8), 0, stream>>>(Wq, WqT, DM, DM);
  transpose_cast_kernel<<<dim3(32, 32), dim3(32, 8), 0, stream>>>(Wo, WoT, DM, DM);
  transpose_cast_kernel<<<dim3(2, 32),  dim3(32, 8), 0, stream>>>(Wk, WkT, DM, DK);
  transpose_cast_kernel<<<dim3(2, 32),  dim3(32, 8), 0, stream>>>(Wv, WvT, DM, DK);

  // K/V projection with fused fragment-linear emit (no separate repack)
  kvproj_kernel<<<dim3(M_ / 64, 2), 256, 0, stream>>>(
      Xkbf, Xvbf, WkT, WvT, bk, bv, KFp, VFp);

  // Q projection, pre-scaled by 1/sqrt(dk) * log2(e) (softmax runs in exp2 domain)
  gemm_bf16_kernel<0><<<dim3(M_ / 128, DM / 64), 256, 0, stream>>>(
      Xqbf, WqT, bq, Qbf, M_, DM, DM, 0.125f * 1.44269504088896f);

  attn_kernel<<<dim3(64, H_, B_), 256, 0, stream>>>(Qbf, KFp, VFp, AObf);

  gemm_bf16_kernel<1><<<dim3(M_ / 128, DM / 64), 256, 0, stream>>>(
      AObf, WoT, bo, d_out, M_, DM, DM, 1.0f);
}